// Round 2
// baseline (1148.690 us; speedup 1.0000x reference)
//
#include <hip/hip_runtime.h>
#include <hip/hip_bf16.h>

// ---------------------------------------------------------------------------
// Transformer block: LN1 -> per-head QKV -> attention -> Wo(+x) -> LN2 ->
//                    FFN1(ReLU) -> FFN2(+x1) -> out
// B=4, S=1024, D=768, H=12, DH=768 (head_dim == D!), DF=3072. fp32 I/O,
// bf16 MFMA compute. Attention chunked per batch to fit 256 MiB workspace.
//
// All GEMMs use one kernel: C = A[M,K] * Bt[N,K]^T, bf16 in, fp32 accum,
// 128x128 tile, BK=32, 4 waves (64x64 each, 4x4 16x16x32 MFMA frags),
// global_load_lds width-16 staging into linear LDS (m97 structure).
// ---------------------------------------------------------------------------

typedef __attribute__((ext_vector_type(8))) __bf16 bf16x8;
typedef __attribute__((ext_vector_type(4))) float f32x4;
typedef __attribute__((ext_vector_type(4))) unsigned short ushort4_t;

#define DEV __device__ __forceinline__

DEV unsigned short f2bf(float f) {
    __hip_bfloat16 h = __float2bfloat16(f);
    return *reinterpret_cast<unsigned short*>(&h);
}
DEV float bf2f(unsigned short u) {
    return __uint_as_float(((unsigned int)u) << 16);
}

DEV void gld16(const void* g, void* l) {
    __builtin_amdgcn_global_load_lds(
        (const __attribute__((address_space(1))) void*)g,
        (__attribute__((address_space(3))) void*)l, 16, 0, 0);
}

// ---------------------------------------------------------------------------
// transpose + fp32->bf16: in [batch][R][C] f32 -> out [batch][C][R] bf16
// grid: (C/32, R/32, batch), block 256 (32x8)
// ---------------------------------------------------------------------------
__global__ __launch_bounds__(256) void transpose_f2b(
    const float* __restrict__ in, unsigned short* __restrict__ outb, int R, int C)
{
    const size_t boff = (size_t)blockIdx.z * R * C;
    __shared__ float tile[32][33];
    const int c0 = blockIdx.x * 32, r0 = blockIdx.y * 32;
    const int tx = threadIdx.x & 31, ty = threadIdx.x >> 5;
#pragma unroll
    for (int i = 0; i < 32; i += 8)
        tile[ty + i][tx] = in[boff + (size_t)(r0 + ty + i) * C + c0 + tx];
    __syncthreads();
#pragma unroll
    for (int i = 0; i < 32; i += 8)
        outb[boff + (size_t)(c0 + ty + i) * R + r0 + tx] = f2bf(tile[tx][ty + i]);
}

// ---------------------------------------------------------------------------
// LayerNorm over 768 cols, fp32 in -> bf16 out. One block (256 thr) per row.
// ---------------------------------------------------------------------------
__global__ __launch_bounds__(256) void layernorm768(
    const float* __restrict__ in, const float* __restrict__ g,
    const float* __restrict__ be, unsigned short* __restrict__ outb)
{
    const size_t rowoff = (size_t)blockIdx.x * 768;
    const float* xr = in + rowoff;
    const int t = threadIdx.x;
    float v0 = xr[t], v1 = xr[t + 256], v2 = xr[t + 512];
    __shared__ float red[8];
    float s = v0 + v1 + v2;
#pragma unroll
    for (int o = 32; o; o >>= 1) s += __shfl_down(s, o);
    if ((t & 63) == 0) red[t >> 6] = s;
    __syncthreads();
    float mu = (red[0] + red[1] + red[2] + red[3]) * (1.0f / 768.0f);
    float d0 = v0 - mu, d1 = v1 - mu, d2 = v2 - mu;
    float q = d0 * d0 + d1 * d1 + d2 * d2;
#pragma unroll
    for (int o = 32; o; o >>= 1) q += __shfl_down(q, o);
    if ((t & 63) == 0) red[4 + (t >> 6)] = q;
    __syncthreads();
    float rs = rsqrtf((red[4] + red[5] + red[6] + red[7]) * (1.0f / 768.0f) + 1e-5f);
    outb[rowoff + t]       = f2bf(d0 * rs * g[t]       + be[t]);
    outb[rowoff + t + 256] = f2bf(d1 * rs * g[t + 256] + be[t + 256]);
    outb[rowoff + t + 512] = f2bf(d2 * rs * g[t + 512] + be[t + 512]);
}

// ---------------------------------------------------------------------------
// In-place row softmax, width 1024, bf16. One block (256 thr) per row.
// ---------------------------------------------------------------------------
__global__ __launch_bounds__(256) void softmax1024(unsigned short* __restrict__ p)
{
    unsigned short* row = p + (size_t)blockIdx.x * 1024;
    const int t = threadIdx.x;
    ushort4_t uv = *(const ushort4_t*)(row + t * 4);
    float v[4];
    float m = -3.4e38f;
#pragma unroll
    for (int i = 0; i < 4; i++) { v[i] = bf2f(uv[i]); m = fmaxf(m, v[i]); }
    __shared__ float red[8];
#pragma unroll
    for (int o = 32; o; o >>= 1) m = fmaxf(m, __shfl_down(m, o));
    if ((t & 63) == 0) red[t >> 6] = m;
    __syncthreads();
    m = fmaxf(fmaxf(red[0], red[1]), fmaxf(red[2], red[3]));
    float s = 0.f;
#pragma unroll
    for (int i = 0; i < 4; i++) { v[i] = __expf(v[i] - m); s += v[i]; }
#pragma unroll
    for (int o = 32; o; o >>= 1) s += __shfl_down(s, o);
    if ((t & 63) == 0) red[4 + (t >> 6)] = s;
    __syncthreads();
    float inv = 1.f / (red[4] + red[5] + red[6] + red[7]);
    ushort4_t ov;
#pragma unroll
    for (int i = 0; i < 4; i++) ov[i] = f2bf(v[i] * inv);
    *(ushort4_t*)(row + t * 4) = ov;
}

// ---------------------------------------------------------------------------
// GEMM: C[M,N] = A[M,K] (row-major bf16, lda) * Bt[N,K]^T (row-major bf16, ldb)
// Batched via blockIdx.z: off = (z/zdiv)*s1 + (z%zdiv)*s2 per matrix.
// MODE_BF16:  out bf16 [cOff + m*ldc + n] = relu?(acc*scale + bias[n])
// MODE_VT:    out bf16 [cOff + n*1024 + m]  (transposed store, M<=1024)
// MODE_F32RES:out f32  [cOff + m*ldc + n] = acc*scale + bias[n] + res[m*ldr+n]
// ---------------------------------------------------------------------------
enum { MODE_BF16 = 0, MODE_VT = 1, MODE_F32RES = 2 };

template <int MODE, bool RELU>
__global__ __launch_bounds__(256) void gemm_bt(
    const unsigned short* __restrict__ A, int lda,
    const unsigned short* __restrict__ Bt, int ldb,
    void* __restrict__ Cout, int ldc,
    const float* __restrict__ bias,
    const float* __restrict__ res, int ldr,
    float scale, int K, int zdiv,
    long long sA1, long long sA2, long long sB1, long long sB2,
    long long sC1, long long sC2, long long sBias)
{
    const int z = blockIdx.z, zq = z / zdiv, zr = z % zdiv;
    A  += (size_t)zq * sA1 + (size_t)zr * sA2;
    Bt += (size_t)zq * sB1 + (size_t)zr * sB2;
    const size_t cOff = (size_t)zq * sC1 + (size_t)zr * sC2;
    const float* biasp = bias ? bias + (size_t)zr * sBias : nullptr;

    const int m0 = blockIdx.y * 128, n0 = blockIdx.x * 128;

    __shared__ __align__(16) unsigned short As[128 * 32];
    __shared__ __align__(16) unsigned short Bs[128 * 32];

    const int t = threadIdx.x, lane = t & 63, wave = t >> 6;
    const int wr = wave >> 1, wc = wave & 1;

    f32x4 zero = {0.f, 0.f, 0.f, 0.f};
    f32x4 acc[4][4];
#pragma unroll
    for (int i = 0; i < 4; i++)
#pragma unroll
        for (int j = 0; j < 4; j++) acc[i][j] = zero;

    // staging map: thread t covers tile bytes [t*16, t*16+16); row = byte/64
    const int r0 = t >> 2;              // (t*16)/64
    const int ce = (t & 3) * 8;         // elem col within 32-elem row
    const int kq = (lane >> 4) * 8, rr = lane & 15;

    for (int k0 = 0; k0 < K; k0 += 32) {
        __syncthreads();   // protect LDS from previous iteration's readers
        {
            const unsigned short* ga0 = A  + (size_t)(m0 + r0) * lda      + k0 + ce;
            const unsigned short* ga1 = A  + (size_t)(m0 + 64 + r0) * lda + k0 + ce;
            const unsigned short* gb0 = Bt + (size_t)(n0 + r0) * ldb      + k0 + ce;
            const unsigned short* gb1 = Bt + (size_t)(n0 + 64 + r0) * ldb + k0 + ce;
            char* la = (char*)As;
            char* lb = (char*)Bs;
            gld16(ga0, la + wave * 1024);
            gld16(ga1, la + 4096 + wave * 1024);
            gld16(gb0, lb + wave * 1024);
            gld16(gb1, lb + 4096 + wave * 1024);
        }
        __syncthreads();   // drains vmcnt -> LDS tile ready

        bf16x8 a[4], b[4];
#pragma unroll
        for (int i = 0; i < 4; i++) {
            a[i] = *(const bf16x8*)(As + (wr * 64 + i * 16 + rr) * 32 + kq);
            b[i] = *(const bf16x8*)(Bs + (wc * 64 + i * 16 + rr) * 32 + kq);
        }
#pragma unroll
        for (int i = 0; i < 4; i++)
#pragma unroll
            for (int j = 0; j < 4; j++)
                acc[i][j] = __builtin_amdgcn_mfma_f32_16x16x32_bf16(a[i], b[j], acc[i][j], 0, 0, 0);
    }

    // epilogue; C/D frag: col = lane&15, row = 4*(lane>>4) + reg   [m89]
    const int cr = (lane >> 4) * 4, cc = lane & 15;
#pragma unroll
    for (int i = 0; i < 4; i++) {
        const int rowb = m0 + wr * 64 + i * 16 + cr;
#pragma unroll
        for (int j = 0; j < 4; j++) {
            const int col = n0 + wc * 64 + j * 16 + cc;
            const float bv = biasp ? biasp[col] : 0.f;
            if (MODE == MODE_VT) {
                ushort4_t pk;
#pragma unroll
                for (int r = 0; r < 4; r++) {
                    float v = acc[i][j][r] * scale + bv;
                    if (RELU) v = fmaxf(v, 0.f);
                    pk[r] = f2bf(v);
                }
                *(ushort4_t*)((unsigned short*)Cout + cOff +
                              (size_t)col * 1024 + rowb) = pk;
            } else {
#pragma unroll
                for (int r = 0; r < 4; r++) {
                    float v = acc[i][j][r] * scale + bv;
                    if (RELU) v = fmaxf(v, 0.f);
                    const int row = rowb + r;
                    if (MODE == MODE_BF16) {
                        ((unsigned short*)Cout)[cOff + (size_t)row * ldc + col] = f2bf(v);
                    } else {
                        ((float*)Cout)[cOff + (size_t)row * ldc + col] =
                            v + res[(size_t)row * ldr + col];
                    }
                }
            }
        }
    }
}

__global__ void ws_too_small(float* o, float v) { o[0] = v; }

// ---------------------------------------------------------------------------
extern "C" void kernel_launch(void* const* d_in, const int* in_sizes, int n_in,
                              void* d_out, int out_size, void* d_ws, size_t ws_size,
                              hipStream_t stream)
{
    const float* x   = (const float*)d_in[0];
    const float* Wq  = (const float*)d_in[1];
    const float* bq  = (const float*)d_in[2];
    const float* Wk  = (const float*)d_in[3];
    const float* bk  = (const float*)d_in[4];
    const float* Wv  = (const float*)d_in[5];
    const float* bv  = (const float*)d_in[6];
    const float* Wo  = (const float*)d_in[7];
    const float* bo  = (const float*)d_in[8];
    const float* W1  = (const float*)d_in[9];
    const float* b1  = (const float*)d_in[10];
    const float* W2  = (const float*)d_in[11];
    const float* b2  = (const float*)d_in[12];
    const float* g1  = (const float*)d_in[13];
    const float* be1 = (const float*)d_in[14];
    const float* g2  = (const float*)d_in[15];
    const float* be2 = (const float*)d_in[16];
    float* out = (float*)d_out;

    // --- workspace layout (peak 229,638,144 B < 256 MiB) ---
    char* ws = (char*)d_ws;
    unsigned short* WQT = (unsigned short*)(ws);             // [12][768][768] (e-major)
    unsigned short* WKT = (unsigned short*)(ws + 14155776);
    unsigned short* WVT = (unsigned short*)(ws + 28311552);
    unsigned short* WOT = (unsigned short*)(ws + 42467328);  // [768][9216]
    unsigned short* W1T = (unsigned short*)(ws + 56623104);  // [3072][768]
    unsigned short* W2T = (unsigned short*)(ws + 61341696);  // [768][3072]
    unsigned short* HB  = (unsigned short*)(ws + 66060288);  // [4096][768]  LN1 out
    unsigned short* CTX = (unsigned short*)(ws + 72351744);  // [4096][9216] ctx concat
    // per-batch attention scratch (reused 4x):
    unsigned short* QBb = (unsigned short*)(ws + 147849216); // [12][1024][768]
    unsigned short* KBb = (unsigned short*)(ws + 166723584); // [12][1024][768]
    unsigned short* SCb = (unsigned short*)(ws + 185597952); // [12][1024][1024]
    unsigned short* VTb = (unsigned short*)(ws + 210763776); // [12][768][1024]
    const size_t NEED = 229638144;

    if (ws_size < NEED) {   // diagnostic: absmax in the log will equal ws_size
        hipMemsetAsync(d_out, 0, (size_t)out_size * sizeof(float), stream);
        ws_too_small<<<1, 1, 0, stream>>>(out, (float)ws_size);
        return;
    }

    // post-attention reuse of the per-batch scratch region:
    float*          X1  = (float*)(ws + 147849216);          // [4096][768] f32
    unsigned short* H2B = (unsigned short*)(ws + 160432128); // [4096][768]
    unsigned short* FFN = (unsigned short*)(ws + 166723584); // [4096][3072]

    // weights -> bf16, transposed to [N][K]
    transpose_f2b<<<dim3(24, 24, 12), 256, 0, stream>>>(Wq, WQT, 768, 768);
    transpose_f2b<<<dim3(24, 24, 12), 256, 0, stream>>>(Wk, WKT, 768, 768);
    transpose_f2b<<<dim3(24, 24, 12), 256, 0, stream>>>(Wv, WVT, 768, 768);
    transpose_f2b<<<dim3(24, 288, 1), 256, 0, stream>>>(Wo, WOT, 9216, 768);
    transpose_f2b<<<dim3(96, 24, 1), 256, 0, stream>>>(W1, W1T, 768, 3072);
    transpose_f2b<<<dim3(24, 96, 1), 256, 0, stream>>>(W2, W2T, 3072, 768);

    layernorm768<<<4096, 256, 0, stream>>>(x, g1, be1, HB);

    // ---- attention, chunked per batch b ----
    for (int b = 0; b < 4; ++b) {
        const unsigned short* HBb = HB + (size_t)b * 786432;   // [1024][768]

        // Q_b[h][s][e] = LN1_b @ Wq[h] + bq[h]
        gemm_bt<MODE_BF16, false><<<dim3(6, 8, 12), 256, 0, stream>>>(
            HBb, 768, WQT, 768, QBb, 768, bq, nullptr, 0, 1.0f, 768, 12,
            0, 0, 0, 589824, 0, 786432, 768);
        // K_b[h][t][e]
        gemm_bt<MODE_BF16, false><<<dim3(6, 8, 12), 256, 0, stream>>>(
            HBb, 768, WKT, 768, KBb, 768, bk, nullptr, 0, 1.0f, 768, 12,
            0, 0, 0, 589824, 0, 786432, 768);

        // scores_b[h][s][t] = scale * Q.K^T
        gemm_bt<MODE_BF16, false><<<dim3(8, 8, 12), 256, 0, stream>>>(
            QBb, 768, KBb, 768, SCb, 1024, nullptr, nullptr, 0,
            0.03608439182435161f, 768, 12,
            0, 786432, 0, 786432, 0, 1048576, 0);

        softmax1024<<<12288, 256, 0, stream>>>(SCb);

        // V^T_b[h][e][s] (transposed-store epilogue)
        gemm_bt<MODE_VT, false><<<dim3(6, 8, 12), 256, 0, stream>>>(
            HBb, 768, WVT, 768, VTb, 0, bv, nullptr, 0, 1.0f, 768, 12,
            0, 0, 0, 589824, 0, 786432, 768);

        // ctx[b*1024+s][h*768+e] = P @ V
        gemm_bt<MODE_BF16, false><<<dim3(6, 8, 12), 256, 0, stream>>>(
            SCb, 1024, VTb, 1024, CTX + (size_t)b * 9437184, 9216,
            nullptr, nullptr, 0, 1.0f, 1024, 12,
            0, 1048576, 0, 786432, 0, 768, 0);
    }

    // x1 = x + ctx @ Wo + bo   (f32)
    gemm_bt<MODE_F32RES, false><<<dim3(6, 32, 1), 256, 0, stream>>>(
        CTX, 9216, WOT, 9216, X1, 768, bo, x, 768, 1.0f, 9216, 1,
        0, 0, 0, 0, 0, 0, 0);

    layernorm768<<<4096, 256, 0, stream>>>(X1, g2, be2, H2B);

    // ffn1 = relu(h2 @ W1 + b1)
    gemm_bt<MODE_BF16, true><<<dim3(24, 32, 1), 256, 0, stream>>>(
        H2B, 768, W1T, 768, FFN, 3072, b1, nullptr, 0, 1.0f, 768, 1,
        0, 0, 0, 0, 0, 0, 0);

    // out = x1 + ffn1 @ W2 + b2
    gemm_bt<MODE_F32RES, false><<<dim3(6, 32, 1), 256, 0, stream>>>(
        FFN, 3072, W2T, 3072, out, 768, b2, X1, 768, 1.0f, 3072, 1,
        0, 0, 0, 0, 0, 0, 0);
}